// Round 12
// baseline (846.370 us; speedup 1.0000x reference)
//
#include <hip/hip_runtime.h>
#include <hip/hip_bf16.h>

typedef float f32x4 __attribute__((ext_vector_type(4)));
typedef short short8 __attribute__((ext_vector_type(8)));

#define CC   512
#define PIX  4096           // 64*64
#define XHROWBYTES 4224     // 66 cols * 64 B
#define XHBYTES    16896    // 4 rows * 4224

__device__ __forceinline__ unsigned short f2bf(float f){
    __hip_bfloat16 h = __float2bfloat16(f);
    return __builtin_bit_cast(unsigned short, h);
}
__device__ __forceinline__ unsigned pk2(float a, float b){
    return (unsigned)f2bf(a) | ((unsigned)f2bf(b) << 16);
}
__device__ __forceinline__ void mfma_bf16(f32x4& c, short8 a, short8 b){
    asm("v_mfma_f32_16x16x32_bf16 %0, %1, %2, %0" : "+v"(c) : "v"(a), "v"(b));
}

// ---------------- styles: s[b,c] = (1/sqrt(512)) * w[b,:] @ sw[c,:] + sb[c] ----
__global__ void k_style3(const float* __restrict__ w,
                         const float* __restrict__ sw0, const float* __restrict__ sb0, float* __restrict__ o0,
                         const float* __restrict__ sw1, const float* __restrict__ sb1, float* __restrict__ o1,
                         const float* __restrict__ sw2, const float* __restrict__ sb2, float* __restrict__ o2){
    __shared__ float wl[512];
    const int b = blockIdx.x, l = blockIdx.y, tid = threadIdx.x;
    const float* sw = (l==0) ? sw0 : (l==1 ? sw1 : sw2);
    const float* sb = (l==0) ? sb0 : (l==1 ? sb1 : sb2);
    float* so       = (l==0) ? o0  : (l==1 ? o1  : o2);
    wl[tid]       = w[b*512 + tid];
    wl[tid + 256] = w[b*512 + 256 + tid];
    __syncthreads();
    const float c = 0.044194173824159216f; // 1/sqrt(512)
    for (int cc = tid; cc < 512; cc += 256){
        const float4* row = (const float4*)(sw + cc*512);
        float acc = 0.f;
        #pragma unroll 4
        for (int dd = 0; dd < 128; ++dd){
            float4 v = row[dd];
            float4 wv = ((const float4*)wl)[dd];
            acc += v.x*wv.x + v.y*wv.y + v.z*wv.z + v.w*wv.w;
        }
        so[b*512 + cc] = acc * c + sb[cc];
    }
}

// ---------------- W2[o,i] = c^2 * sum_t conv_w[o,i,t]^2  (both layers) --------
__global__ void k_w2(const float* __restrict__ cw1, const float* __restrict__ cw2,
                     float* __restrict__ w2_1, float* __restrict__ w2_2){
    int gid = blockIdx.x*256 + threadIdx.x;     // 2 * 262144
    int layer = gid >> 18; int r = gid & 262143;
    const float* cw = layer ? cw2 : cw1;
    float* w2 = layer ? w2_2 : w2_1;
    const float c2 = 1.0f/4608.0f;
    const float* p = cw + r*9;
    float sum = 0.f;
    #pragma unroll
    for (int t=0;t<9;++t){ float v = p[t]; sum += v*v; }
    w2[r] = sum * c2;
}

// ---------------- d[b,o] = rsqrt( sum_i W2[o,i]*s[b,i]^2 + 1e-8 ) -------------
__global__ void k_demod2(const float* __restrict__ w21, const float* __restrict__ w22,
                         const float* __restrict__ s1,  const float* __restrict__ s2,
                         float* __restrict__ d1, float* __restrict__ d2){
    __shared__ float s2l[512];
    const int b = blockIdx.x, l = blockIdx.y, o = threadIdx.x;
    const float* w2 = l ? w22 : w21;
    const float* s  = l ? s2  : s1;
    float* d        = l ? d2  : d1;
    float sv = s[b*512 + o]; s2l[o] = sv*sv;
    __syncthreads();
    const float4* row = (const float4*)(w2 + o*512);
    const float4* sq  = (const float4*)s2l;
    float acc = 0.f;
    #pragma unroll 4
    for (int i=0;i<128;++i){
        float4 a = row[i], bq = sq[i];
        acc += a.x*bq.x + a.y*bq.y + a.z*bq.z + a.w*bq.w;
    }
    d[b*512 + o] = rsqrtf(acc + 1e-8f);
}

// ---------------- pack conv weights -> MFMA A-fragment order, bf16 ------------
// layout: wpk[t(9)][cb(16)][ofr(32)][lane(64)][j(8)] ; element =
//   c * conv_w[o = ofr*16 + (lane&15)][i = cb*32 + (lane>>4)*8 + j][t/3][t%3]
__global__ void k_pack(const float* __restrict__ cw1, const float* __restrict__ cw2,
                       uint4* __restrict__ wpk1, uint4* __restrict__ wpk2){
    int gid = blockIdx.x*256 + threadIdx.x;     // 2 * 294912
    int layer = (gid >= 294912);
    int r = layer ? gid - 294912 : gid;
    const float* cw = layer ? cw2 : cw1;
    uint4* dst = layer ? wpk2 : wpk1;
    int lane = r & 63;
    int ofr  = (r>>6) & 31;
    int cb   = (r>>11) & 15;
    int t    = r>>15;
    int o  = ofr*16 + (lane&15);
    int i0 = cb*32 + (lane>>4)*8;
    const float c = 0.014731391274719738f; // 1/sqrt(4608)
    const float* src = cw + (o*512 + i0)*9 + t;
    float f[8];
    #pragma unroll
    for (int j=0;j<8;++j) f[j] = src[j*9]*c;
    uint4 wv;
    wv.x = pk2(f[0],f[1]); wv.y = pk2(f[2],f[3]);
    wv.z = pk2(f[4],f[5]); wv.w = pk2(f[6],f[7]);
    dst[r] = wv;
}

// ---------------- the modulated 3x3 conv (implicit GEMM, bf16 MFMA) -----------
// grid (4 ob, 32 rowblocks, 16 b), 256 threads (4 waves).
// Block covers 2 output rows x 128 o-channels. Wave wv owns o-range
// [ob*128 + wv*32, +32) over BOTH rows x 64 cols = 128 px: acc[2][8].
// A-traffic = r11 (128 px per A-fetch); acc VGPR halved -> ~3 waves/SIMD.
// Staged tile (round-9-proven): 4 rows (r0-1..r0+2) x 66 cols x 32 ch, 2 bufs.
__global__ __launch_bounds__(256, 2)
void k_conv(const float* __restrict__ x, float* __restrict__ y,
            const unsigned short* __restrict__ wpk, const float* __restrict__ s,
            const float* __restrict__ dmod, const float* __restrict__ noise,
            const float* __restrict__ nsp, const float* __restrict__ bias){
    __shared__ __align__(16) char smem[35840];
    char* xh0 = smem;
    char* xh1 = smem + XHBYTES;
    float* s_lds = (float*)(smem + 2*XHBYTES);          // 512 f32

    const int tid  = threadIdx.x;
    const int ob   = blockIdx.x;        // 0..3: 128-channel o-block
    const int rb   = blockIdx.y;        // 0..31
    const int b    = blockIdx.z;
    const int r0   = rb*2;
    const int lane = tid & 63;
    const int wv   = tid >> 6;          // 0..3: 32-channel o-subgroup
    const int ln15 = lane & 15;
    const int hi   = lane >> 4;

    const float* xb = x + (size_t)b * (512*PIX);

    s_lds[tid]       = s[b*512 + tid];
    s_lds[tid + 256] = s[b*512 + 256 + tid];
    __syncthreads();

    f32x4 acc[2][8];
    #pragma unroll
    for (int mi=0;mi<2;++mi)
        #pragma unroll
        for (int ni=0;ni<8;++ni) acc[mi][ni] = (f32x4)(0.f);

    // B-fragment column byte-offsets (col-XOR swizzle), per (dx+1, colgroup)
    unsigned bcol[3][4];
    #pragma unroll
    for (int dxi=0; dxi<3; ++dxi)
        #pragma unroll
        for (int ni=0; ni<4; ++ni){
            int xcol = ni*16 + ln15 + dxi;
            unsigned a = (unsigned)(xcol*64 + hi*16);
            a ^= (unsigned)(((xcol>>1)&3)<<4);
            bcol[dxi][ni] = a;
        }

    const int scol   = tid & 63;        // staging: fixed col
    const int schunk = (tid>>6) & 3;    // staging: fixed 8-channel chunk
    unsigned wcol = (unsigned)((scol+1)*64 + schunk*16);
    wcol ^= (unsigned)((((scol+1)>>1)&3)<<4);

    auto stage = [&](int cb, char* dst){
        float sv[8];
        #pragma unroll
        for (int j=0;j<8;++j) sv[j] = s_lds[cb*32 + schunk*8 + j];
        const float* srcbase = xb + (size_t)(cb*32 + schunk*8)*PIX + scol;
        #pragma unroll
        for (int row=0; row<4; ++row){
            int gr = r0 - 1 + row;
            uint4 wq = make_uint4(0u,0u,0u,0u);
            if (0 <= gr && gr < 64){
                const float* sp = srcbase + gr*64;
                float f0 = sp[0*PIX]*sv[0], f1 = sp[1*PIX]*sv[1];
                float f2 = sp[2*PIX]*sv[2], f3 = sp[3*PIX]*sv[3];
                float f4 = sp[4*PIX]*sv[4], f5 = sp[5*PIX]*sv[5];
                float f6 = sp[6*PIX]*sv[6], f7 = sp[7*PIX]*sv[7];
                wq.x = pk2(f0,f1); wq.y = pk2(f2,f3);
                wq.z = pk2(f4,f5); wq.w = pk2(f6,f7);
            }
            *(uint4*)(dst + row*XHROWBYTES + wcol) = wq;
        }
        if (tid < 32){  // halo cols (image col -1 and 64) -> zeros, 4 rows
            int row = tid>>3; int hc = (tid&4) ? 65 : 0; int ck = tid&3;
            unsigned a = (unsigned)((row*66 + hc)*64 + ck*16);
            a ^= (unsigned)(((hc>>1)&3)<<4);
            *(uint4*)(dst + a) = make_uint4(0u,0u,0u,0u);
        }
    };

    stage(0, xh0);

    // A-fragment base: ofr0 = (ob*128 + wv*32)/16 = ob*8 + wv*2
    const short8* wpf = (const short8*)wpk + (size_t)(ob*8 + wv*2)*64 + lane;

    #pragma unroll 2
    for (int cb=0; cb<16; ++cb){
        __syncthreads();                         // staged buffer ready; prev reads done
        if (cb+1 < 16) stage(cb+1, (cb&1) ? xh0 : xh1);
        const char* cur = (cb&1) ? xh1 : xh0;
        const short8* wp = wpf + (size_t)cb*(32*64);
        #pragma unroll
        for (int t=0; t<9; ++t){
            const int dxi = t%3;                 // dx+1; t/3 = dy+1
            short8 Af[2];
            #pragma unroll
            for (int mi=0;mi<2;++mi) Af[mi] = wp[(size_t)t*(16*32*64) + mi*64];
            const char* rbase0 = cur + (t/3)*XHROWBYTES;      // output row r0
            const char* rbase1 = rbase0 + XHROWBYTES;         // output row r0+1
            short8 Bf[8];
            #pragma unroll
            for (int ni=0;ni<4;++ni) Bf[ni]   = *(const short8*)(rbase0 + bcol[dxi][ni]);
            #pragma unroll
            for (int ni=0;ni<4;++ni) Bf[4+ni] = *(const short8*)(rbase1 + bcol[dxi][ni]);
            #pragma unroll
            for (int ni=0;ni<8;++ni)
                #pragma unroll
                for (int mi=0;mi<2;++mi)
                    mfma_bf16(acc[mi][ni], Af[mi], Bf[ni]);
        }
    }

    // epilogue: y = lrelu(d*acc + ns*noise + bias); d/bias from global (L2-hot)
    const int obase = ob*128 + wv*32;
    const float nsv = nsp[0];
    const float* dgl = dmod + b*512 + obase;
    const float* bgl = bias + obase;
    float nz[8];
    #pragma unroll
    for (int ni=0;ni<8;++ni){
        int row = r0 + (ni>>2);
        nz[ni] = nsv * noise[b*PIX + row*64 + (ni&3)*16 + ln15];
    }
    float* yb = y + ((size_t)(b*512 + obase))*PIX;
    #pragma unroll
    for (int mi=0;mi<2;++mi){
        float dv[4], bv[4];
        #pragma unroll
        for (int r=0;r<4;++r){
            int ol = mi*16 + hi*4 + r;
            dv[r] = dgl[ol]; bv[r] = bgl[ol];
        }
        #pragma unroll
        for (int ni=0;ni<8;++ni){
            int row = r0 + (ni>>2);
            int col = (ni&3)*16 + ln15;
            #pragma unroll
            for (int r=0;r<4;++r){
                float v = acc[mi][ni][r]*dv[r] + nz[ni] + bv[r];
                v = fmaxf(v, 0.2f*v);
                yb[(size_t)(mi*16 + hi*4 + r)*PIX + row*64 + col] = v;
            }
        }
    }
}

// ---------------- to_rgb: 1x1 modulated conv (no demod) + bias + lrelu --------
__global__ void k_rgb(const float* __restrict__ x2, const float* __restrict__ srgb,
                      const float* __restrict__ cw, const float* __restrict__ bias,
                      float* __restrict__ out){
    __shared__ float4 wr[512];
    const int b = blockIdx.x, tid = threadIdx.x;
    const float c = 0.044194173824159216f; // 1/sqrt(512)
    for (int cc = tid; cc < 512; cc += 256){
        float sc = srgb[b*512 + cc]*c;
        wr[cc] = make_float4(cw[cc]*sc, cw[512+cc]*sc, cw[1024+cc]*sc, 0.f);
    }
    __syncthreads();
    int px = blockIdx.y*256 + tid;
    const float* xp = x2 + (size_t)b*(512*PIX) + px;
    float a0=0.f, a1=0.f, a2=0.f;
    #pragma unroll 4
    for (int i=0;i<512;++i){
        float xv = xp[(size_t)i*PIX];
        float4 wv = wr[i];
        a0 += wv.x*xv; a1 += wv.y*xv; a2 += wv.z*xv;
    }
    a0 += bias[0]; a1 += bias[1]; a2 += bias[2];
    out[(size_t)(b*3+0)*PIX + px] = fmaxf(a0, 0.2f*a0);
    out[(size_t)(b*3+1)*PIX + px] = fmaxf(a1, 0.2f*a1);
    out[(size_t)(b*3+2)*PIX + px] = fmaxf(a2, 0.2f*a2);
}

extern "C" void kernel_launch(void* const* d_in, const int* in_sizes, int n_in,
                              void* d_out, int out_size, void* d_ws, size_t ws_size,
                              hipStream_t stream) {
    const float* x    = (const float*)d_in[0];
    const float* w    = (const float*)d_in[1];
    const float* n1   = (const float*)d_in[2];
    const float* n2   = (const float*)d_in[3];
    const float* s1w  = (const float*)d_in[4];
    const float* s1b  = (const float*)d_in[5];
    const float* c1w  = (const float*)d_in[6];
    const float* ns1  = (const float*)d_in[7];
    const float* b1   = (const float*)d_in[8];
    const float* s2w  = (const float*)d_in[9];
    const float* s2b  = (const float*)d_in[10];
    const float* c2w  = (const float*)d_in[11];
    const float* ns2  = (const float*)d_in[12];
    const float* b2   = (const float*)d_in[13];
    const float* rw   = (const float*)d_in[14];
    const float* rbv  = (const float*)d_in[15];
    const float* rcw  = (const float*)d_in[16];
    const float* rbias= (const float*)d_in[17];

    float* out_x   = (float*)d_out;
    float* out_rgb = out_x + (size_t)16*512*PIX;

    // workspace layout (round-1-proven, ~146 MB)
    char* ws = (char*)d_ws;
    float* s1   = (float*)(ws + 0);
    float* s2   = (float*)(ws + 32768);
    float* srgb = (float*)(ws + 65536);
    float* d1   = (float*)(ws + 98304);
    float* d2   = (float*)(ws + 131072);
    float* w21  = (float*)(ws + 163840);
    float* w22  = (float*)(ws + 163840 + 1048576);
    unsigned short* wp1 = (unsigned short*)(ws + 2260992);
    unsigned short* wp2 = wp1 + 2359296;
    float* x1   = (float*)(ws + 11698176);

    k_style3<<<dim3(16,3), 256, 0, stream>>>(w, s1w, s1b, s1, s2w, s2b, s2, rw, rbv, srgb);
    k_w2<<<2048, 256, 0, stream>>>(c1w, c2w, w21, w22);
    k_pack<<<2304, 256, 0, stream>>>(c1w, c2w, (uint4*)wp1, (uint4*)wp2);
    k_demod2<<<dim3(16,2), 512, 0, stream>>>(w21, w22, s1, s2, d1, d2);

    dim3 cg(4, 32, 16);
    k_conv<<<cg, 256, 0, stream>>>(x,  x1,    wp1, s1, d1, n1, ns1, b1);
    k_conv<<<cg, 256, 0, stream>>>(x1, out_x, wp2, s2, d2, n2, ns2, b2);
    k_rgb<<<dim3(16,16), 256, 0, stream>>>(out_x, srgb, rcw, rbias, out_rgb);
}

// Round 13
// 839.478 us; speedup vs baseline: 1.0082x; 1.0082x over previous
//
#include <hip/hip_runtime.h>
#include <hip/hip_bf16.h>

typedef float f32x4 __attribute__((ext_vector_type(4)));
typedef short short8 __attribute__((ext_vector_type(8)));

#define CC    512
#define PIX   4096          // 64*64
#define ROWB  4224          // 66 cols * 64 B
#define TILE6 25344         // 6 rows * 4224 (k_stage_g tile)
#define TILE4 16896         // 4 rows * 4224 (conv LDS tile)

__device__ __forceinline__ unsigned short f2bf(float f){
    __hip_bfloat16 h = __float2bfloat16(f);
    return __builtin_bit_cast(unsigned short, h);
}
__device__ __forceinline__ unsigned pk2(float a, float b){
    return (unsigned)f2bf(a) | ((unsigned)f2bf(b) << 16);
}
__device__ __forceinline__ void mfma_bf16(f32x4& c, short8 a, short8 b){
    asm("v_mfma_f32_16x16x32_bf16 %0, %1, %2, %0" : "+v"(c) : "v"(a), "v"(b));
}
__device__ __forceinline__ void gl_lds16(const void* g, void* l){
    __builtin_amdgcn_global_load_lds(
        (const __attribute__((address_space(1))) unsigned int*)g,
        (__attribute__((address_space(3))) unsigned int*)l, 16, 0, 0);
}

// ---------------- styles: s[b,c] = (1/sqrt(512)) * w[b,:] @ sw[c,:] + sb[c] ----
__global__ void k_style3(const float* __restrict__ w,
                         const float* __restrict__ sw0, const float* __restrict__ sb0, float* __restrict__ o0,
                         const float* __restrict__ sw1, const float* __restrict__ sb1, float* __restrict__ o1,
                         const float* __restrict__ sw2, const float* __restrict__ sb2, float* __restrict__ o2){
    __shared__ float wl[512];
    const int b = blockIdx.x, l = blockIdx.y, tid = threadIdx.x;
    const float* sw = (l==0) ? sw0 : (l==1 ? sw1 : sw2);
    const float* sb = (l==0) ? sb0 : (l==1 ? sb1 : sb2);
    float* so       = (l==0) ? o0  : (l==1 ? o1  : o2);
    wl[tid]       = w[b*512 + tid];
    wl[tid + 256] = w[b*512 + 256 + tid];
    __syncthreads();
    const float c = 0.044194173824159216f; // 1/sqrt(512)
    for (int cc = tid; cc < 512; cc += 256){
        const float4* row = (const float4*)(sw + cc*512);
        float acc = 0.f;
        #pragma unroll 4
        for (int dd = 0; dd < 128; ++dd){
            float4 v = row[dd];
            float4 wv = ((const float4*)wl)[dd];
            acc += v.x*wv.x + v.y*wv.y + v.z*wv.z + v.w*wv.w;
        }
        so[b*512 + cc] = acc * c + sb[cc];
    }
}

// ---------------- W2[o,i] = c^2 * sum_t conv_w[o,i,t]^2  (both layers) --------
__global__ void k_w2(const float* __restrict__ cw1, const float* __restrict__ cw2,
                     float* __restrict__ w2_1, float* __restrict__ w2_2){
    int gid = blockIdx.x*256 + threadIdx.x;     // 2 * 262144
    int layer = gid >> 18; int r = gid & 262143;
    const float* cw = layer ? cw2 : cw1;
    float* w2 = layer ? w2_2 : w2_1;
    const float c2 = 1.0f/4608.0f;
    const float* p = cw + r*9;
    float sum = 0.f;
    #pragma unroll
    for (int t=0;t<9;++t){ float v = p[t]; sum += v*v; }
    w2[r] = sum * c2;
}

// ---------------- d[b,o] = rsqrt( sum_i W2[o,i]*s[b,i]^2 + 1e-8 ) -------------
__global__ void k_demod2(const float* __restrict__ w21, const float* __restrict__ w22,
                         const float* __restrict__ s1,  const float* __restrict__ s2,
                         float* __restrict__ d1, float* __restrict__ d2){
    __shared__ float s2l[512];
    const int b = blockIdx.x, l = blockIdx.y, o = threadIdx.x;
    const float* w2 = l ? w22 : w21;
    const float* s  = l ? s2  : s1;
    float* d        = l ? d2  : d1;
    float sv = s[b*512 + o]; s2l[o] = sv*sv;
    __syncthreads();
    const float4* row = (const float4*)(w2 + o*512);
    const float4* sq  = (const float4*)s2l;
    float acc = 0.f;
    #pragma unroll 4
    for (int i=0;i<128;++i){
        float4 a = row[i], bq = sq[i];
        acc += a.x*bq.x + a.y*bq.y + a.z*bq.z + a.w*bq.w;
    }
    d[b*512 + o] = rsqrtf(acc + 1e-8f);
}

// ---------------- pack conv weights -> MFMA A-fragment order, bf16 ------------
// layout: wpk[t(9)][cb(16)][ofr(32)][lane(64)][j(8)] ; element =
//   c * conv_w[o = ofr*16 + (lane&15)][i = cb*32 + (lane>>4)*8 + j][t/3][t%3]
__global__ void k_pack(const float* __restrict__ cw1, const float* __restrict__ cw2,
                       uint4* __restrict__ wpk1, uint4* __restrict__ wpk2){
    int gid = blockIdx.x*256 + threadIdx.x;     // 2 * 294912
    int layer = (gid >= 294912);
    int r = layer ? gid - 294912 : gid;
    const float* cw = layer ? cw2 : cw1;
    uint4* dst = layer ? wpk2 : wpk1;
    int lane = r & 63;
    int ofr  = (r>>6) & 31;
    int cb   = (r>>11) & 15;
    int t    = r>>15;
    int o  = ofr*16 + (lane&15);
    int i0 = cb*32 + (lane>>4)*8;
    const float c = 0.014731391274719738f; // 1/sqrt(4608)
    const float* src = cw + (o*512 + i0)*9 + t;
    float f[8];
    #pragma unroll
    for (int j=0;j<8;++j) f[j] = src[j*9]*c;
    uint4 wv;
    wv.x = pk2(f[0],f[1]); wv.y = pk2(f[2],f[3]);
    wv.z = pk2(f[4],f[5]); wv.w = pk2(f[6],f[7]);
    dst[r] = wv;
}

// ---------------- pre-stage x*s -> global tiles (round-10-proven, verbatim) ---
// For each (b, RB, cb): 25344B 6-row tile == round-1 stage()'s LDS byte image
// (rows RB*4-1..RB*4+4 stored 0..5, 66 cols w/ halo, XOR-swizzled, bf16(x*s)).
__global__ void k_stage_g(const float* __restrict__ x, const float* __restrict__ s,
                          char* __restrict__ xpg){
    __shared__ float s_lds[512];
    const int tid = threadIdx.x;
    const int rb = blockIdx.x, b = blockIdx.y;
    const int r0 = rb*4;
    s_lds[tid]       = s[b*512 + tid];
    s_lds[tid + 256] = s[b*512 + 256 + tid];
    __syncthreads();
    const int scol   = tid & 63;
    const int schunk = (tid>>6) & 3;
    unsigned wcol = (unsigned)((scol+1)*64 + schunk*16);
    wcol ^= (unsigned)((((scol+1)>>1)&3)<<4);
    const float* xb = x + (size_t)b * (512*PIX);
    for (int cb=0; cb<16; ++cb){
        char* dst = xpg + ((size_t)((b*16 + rb)*16 + cb))*TILE6;
        float sv[8];
        #pragma unroll
        for (int j=0;j<8;++j) sv[j] = s_lds[cb*32 + schunk*8 + j];
        const float* srcbase = xb + (size_t)(cb*32 + schunk*8)*PIX + scol;
        #pragma unroll
        for (int row=0; row<6; ++row){
            int gr = r0 - 1 + row;
            uint4 wq = make_uint4(0u,0u,0u,0u);
            if (0 <= gr && gr < 64){
                const float* sp = srcbase + gr*64;
                float f0 = sp[0*PIX]*sv[0], f1 = sp[1*PIX]*sv[1];
                float f2 = sp[2*PIX]*sv[2], f3 = sp[3*PIX]*sv[3];
                float f4 = sp[4*PIX]*sv[4], f5 = sp[5*PIX]*sv[5];
                float f6 = sp[6*PIX]*sv[6], f7 = sp[7*PIX]*sv[7];
                wq.x = pk2(f0,f1); wq.y = pk2(f2,f3);
                wq.z = pk2(f4,f5); wq.w = pk2(f6,f7);
            }
            *(uint4*)(dst + row*ROWB + wcol) = wq;
        }
        if (tid < 48){  // halo cols (image col -1 and 64) -> zeros
            int row = tid>>3; int hc = (tid&4) ? 65 : 0; int ck = tid&3;
            unsigned a = (unsigned)((row*66 + hc)*64 + ck*16);
            a ^= (unsigned)(((hc>>1)&3)<<4);
            *(uint4*)(dst + a) = make_uint4(0u,0u,0u,0u);
        }
    }
}

// ---------------- the modulated 3x3 conv (implicit GEMM, bf16 MFMA) -----------
// grid (2 obp, 32 rb, 16 b), 256 threads (4 waves). Round-11-proven compute:
// wave wv owns o in [obp*256 + wv*64, +64) over 2 rows x 64 cols: acc[4][8].
// Staging: LINEAR 16896B gl_lds copy of the pre-packed 4-row slice (row offset
// (rb&1)*2 within the 6-row tile). Af(t=0) loaded BEFORE the gl_lds batch so
// the first MFMA never waits on staging (in-order VMEM queue).
__global__ __launch_bounds__(256, 2)
void k_conv(const char* __restrict__ xpg, float* __restrict__ y,
            const unsigned short* __restrict__ wpk,
            const float* __restrict__ dmod, const float* __restrict__ noise,
            const float* __restrict__ nsp, const float* __restrict__ bias){
    __shared__ __align__(16) char smem[2*TILE4];   // 33792 B
    char* xh0 = smem;
    char* xh1 = smem + TILE4;

    const int tid  = threadIdx.x;
    const int obp  = blockIdx.x;        // 0..1: 256-channel o-group
    const int rb   = blockIdx.y;        // 0..31
    const int b    = blockIdx.z;
    const int r0   = rb*2;
    const int lane = tid & 63;
    const int wv   = tid >> 6;          // 0..3: 64-channel o-subgroup
    const int ln15 = lane & 15;
    const int hi   = lane >> 4;

    f32x4 acc[4][8];
    #pragma unroll
    for (int mi=0;mi<4;++mi)
        #pragma unroll
        for (int ni=0;ni<8;++ni) acc[mi][ni] = (f32x4)(0.f);

    // B-fragment column byte-offsets (col-XOR swizzle), per (dx+1, colgroup)
    unsigned bcol[3][4];
    #pragma unroll
    for (int dxi=0; dxi<3; ++dxi)
        #pragma unroll
        for (int ni=0; ni<4; ++ni){
            int xcol = ni*16 + ln15 + dxi;
            unsigned a = (unsigned)(xcol*64 + hi*16);
            a ^= (unsigned)(((xcol>>1)&3)<<4);
            bcol[dxi][ni] = a;
        }

    // 4-row slice (rows r0-1..r0+2) of the 6-row tile for RB=rb>>1
    const char* tbase = xpg + ((size_t)((b*16 + (rb>>1))*16))*TILE6
                            + (size_t)(rb&1)*2*ROWB;
    auto stage = [&](int cb2, char* dstb){
        const char* src = tbase + (size_t)cb2*TILE6;
        #pragma unroll
        for (int k=0;k<4;++k)
            gl_lds16(src + (size_t)(tid + k*256)*16, dstb + (tid + k*256)*16);
        if (tid < 32)
            gl_lds16(src + (size_t)(1024 + tid)*16, dstb + (1024 + tid)*16);
    };

    stage(0, xh0);

    // A-fragment base: ofr0 = (obp*256 + wv*64)/16 = obp*16 + wv*4
    const short8* wpf = (const short8*)wpk + (size_t)(obp*16 + wv*4)*64 + lane;

    #pragma unroll 2
    for (int cb=0; cb<16; ++cb){
        __syncthreads();                         // staged buffer ready; prev reads done
        const short8* wp = wpf + (size_t)cb*(32*64);
        short8 Af[4];
        #pragma unroll
        for (int mi=0;mi<4;++mi) Af[mi] = wp[mi*64];   // t=0 A, before staging loads
        if (cb+1 < 16) stage(cb+1, (cb&1) ? xh0 : xh1);
        const char* cur = (cb&1) ? xh1 : xh0;
        #pragma unroll
        for (int t=0; t<9; ++t){
            const int dxi = t%3;                 // dx+1; t/3 = dy+1
            if (t > 0){
                #pragma unroll
                for (int mi=0;mi<4;++mi) Af[mi] = wp[(size_t)t*(16*32*64) + mi*64];
            }
            const char* rbase0 = cur + (t/3)*ROWB;            // output row r0
            const char* rbase1 = rbase0 + ROWB;               // output row r0+1
            short8 Bf[8];
            #pragma unroll
            for (int ni=0;ni<4;++ni) Bf[ni]   = *(const short8*)(rbase0 + bcol[dxi][ni]);
            #pragma unroll
            for (int ni=0;ni<4;++ni) Bf[4+ni] = *(const short8*)(rbase1 + bcol[dxi][ni]);
            #pragma unroll
            for (int ni=0;ni<8;++ni)
                #pragma unroll
                for (int mi=0;mi<4;++mi)
                    mfma_bf16(acc[mi][ni], Af[mi], Bf[ni]);
        }
    }

    // epilogue: y = lrelu(d*acc + ns*noise + bias); d/bias from global (L2-hot)
    const int obase = obp*256 + wv*64;
    const float nsv = nsp[0];
    const float* dgl = dmod + b*512 + obase;
    const float* bgl = bias + obase;
    float nz[8];
    #pragma unroll
    for (int ni=0;ni<8;++ni){
        int row = r0 + (ni>>2);
        nz[ni] = nsv * noise[b*PIX + row*64 + (ni&3)*16 + ln15];
    }
    float* yb = y + ((size_t)(b*512 + obase))*PIX;
    #pragma unroll
    for (int mi=0;mi<4;++mi){
        float dv[4], bv[4];
        #pragma unroll
        for (int r=0;r<4;++r){
            int ol = mi*16 + hi*4 + r;
            dv[r] = dgl[ol]; bv[r] = bgl[ol];
        }
        #pragma unroll
        for (int ni=0;ni<8;++ni){
            int row = r0 + (ni>>2);
            int col = (ni&3)*16 + ln15;
            #pragma unroll
            for (int r=0;r<4;++r){
                float v = acc[mi][ni][r]*dv[r] + nz[ni] + bv[r];
                v = fmaxf(v, 0.2f*v);
                yb[(size_t)(mi*16 + hi*4 + r)*PIX + row*64 + col] = v;
            }
        }
    }
}

// ---------------- to_rgb: 1x1 modulated conv (no demod) + bias + lrelu --------
__global__ void k_rgb(const float* __restrict__ x2, const float* __restrict__ srgb,
                      const float* __restrict__ cw, const float* __restrict__ bias,
                      float* __restrict__ out){
    __shared__ float4 wr[512];
    const int b = blockIdx.x, tid = threadIdx.x;
    const float c = 0.044194173824159216f; // 1/sqrt(512)
    for (int cc = tid; cc < 512; cc += 256){
        float sc = srgb[b*512 + cc]*c;
        wr[cc] = make_float4(cw[cc]*sc, cw[512+cc]*sc, cw[1024+cc]*sc, 0.f);
    }
    __syncthreads();
    int px = blockIdx.y*256 + tid;
    const float* xp = x2 + (size_t)b*(512*PIX) + px;
    float a0=0.f, a1=0.f, a2=0.f;
    #pragma unroll 4
    for (int i=0;i<512;++i){
        float xv = xp[(size_t)i*PIX];
        float4 wv = wr[i];
        a0 += wv.x*xv; a1 += wv.y*xv; a2 += wv.z*xv;
    }
    a0 += bias[0]; a1 += bias[1]; a2 += bias[2];
    out[(size_t)(b*3+0)*PIX + px] = fmaxf(a0, 0.2f*a0);
    out[(size_t)(b*3+1)*PIX + px] = fmaxf(a1, 0.2f*a1);
    out[(size_t)(b*3+2)*PIX + px] = fmaxf(a2, 0.2f*a2);
}

extern "C" void kernel_launch(void* const* d_in, const int* in_sizes, int n_in,
                              void* d_out, int out_size, void* d_ws, size_t ws_size,
                              hipStream_t stream) {
    const float* x    = (const float*)d_in[0];
    const float* w    = (const float*)d_in[1];
    const float* n1   = (const float*)d_in[2];
    const float* n2   = (const float*)d_in[3];
    const float* s1w  = (const float*)d_in[4];
    const float* s1b  = (const float*)d_in[5];
    const float* c1w  = (const float*)d_in[6];
    const float* ns1  = (const float*)d_in[7];
    const float* b1   = (const float*)d_in[8];
    const float* s2w  = (const float*)d_in[9];
    const float* s2b  = (const float*)d_in[10];
    const float* c2w  = (const float*)d_in[11];
    const float* ns2  = (const float*)d_in[12];
    const float* b2   = (const float*)d_in[13];
    const float* rw   = (const float*)d_in[14];
    const float* rbv  = (const float*)d_in[15];
    const float* rcw  = (const float*)d_in[16];
    const float* rbias= (const float*)d_in[17];

    float* out_x   = (float*)d_out;
    float* out_rgb = out_x + (size_t)16*512*PIX;

    // workspace (round-10-proven layout): xpg = 16*16*16*25344 = 103,809,024 B
    // -> ws end 115.5 MB. f32 intermediate x1 lives in d_out x-region (scratch
    // until conv2 overwrites it with the final x).
    char* ws = (char*)d_ws;
    float* s1   = (float*)(ws + 0);
    float* s2   = (float*)(ws + 32768);
    float* srgb = (float*)(ws + 65536);
    float* d1   = (float*)(ws + 98304);
    float* d2   = (float*)(ws + 131072);
    float* w21  = (float*)(ws + 163840);
    float* w22  = (float*)(ws + 163840 + 1048576);
    unsigned short* wp1 = (unsigned short*)(ws + 2260992);
    unsigned short* wp2 = wp1 + 2359296;
    char* xpg   = ws + 11698176;
    float* x1   = out_x;

    k_style3<<<dim3(16,3), 256, 0, stream>>>(w, s1w, s1b, s1, s2w, s2b, s2, rw, rbv, srgb);
    k_w2<<<2048, 256, 0, stream>>>(c1w, c2w, w21, w22);
    k_pack<<<2304, 256, 0, stream>>>(c1w, c2w, (uint4*)wp1, (uint4*)wp2);
    k_demod2<<<dim3(16,2), 512, 0, stream>>>(w21, w22, s1, s2, d1, d2);

    dim3 cg(2, 32, 16);
    k_stage_g<<<dim3(16,16), 256, 0, stream>>>(x, s1, xpg);
    k_conv<<<cg, 256, 0, stream>>>(xpg, x1, wp1, d1, n1, ns1, b1);
    k_stage_g<<<dim3(16,16), 256, 0, stream>>>(x1, s2, xpg);
    k_conv<<<cg, 256, 0, stream>>>(xpg, out_x, wp2, d2, n2, ns2, b2);
    k_rgb<<<dim3(16,16), 256, 0, stream>>>(out_x, srgb, rcw, rbias, out_rgb);
}

// Round 14
// 835.134 us; speedup vs baseline: 1.0135x; 1.0052x over previous
//
#include <hip/hip_runtime.h>
#include <hip/hip_bf16.h>

typedef float f32x4 __attribute__((ext_vector_type(4)));
typedef short short8 __attribute__((ext_vector_type(8)));

#define CC    512
#define PIX   4096          // 64*64
#define ROWB  4224          // 66 cols * 64 B
#define TILE6 25344         // 6 rows * 4224 (k_stage_g tile)
#define TILE4 16896         // 4 rows * 4224 (conv LDS tile)

__device__ __forceinline__ unsigned short f2bf(float f){
    __hip_bfloat16 h = __float2bfloat16(f);
    return __builtin_bit_cast(unsigned short, h);
}
__device__ __forceinline__ unsigned pk2(float a, float b){
    return (unsigned)f2bf(a) | ((unsigned)f2bf(b) << 16);
}
__device__ __forceinline__ void mfma_bf16(f32x4& c, short8 a, short8 b){
    asm("v_mfma_f32_16x16x32_bf16 %0, %1, %2, %0" : "+v"(c) : "v"(a), "v"(b));
}
__device__ __forceinline__ void gl_lds16(const void* g, void* l){
    __builtin_amdgcn_global_load_lds(
        (const __attribute__((address_space(1))) unsigned int*)g,
        (__attribute__((address_space(3))) unsigned int*)l, 16, 0, 0);
}

// ---------------- styles: s[b,c] = (1/sqrt(512)) * w[b,:] @ sw[c,:] + sb[c] ----
__global__ void k_style3(const float* __restrict__ w,
                         const float* __restrict__ sw0, const float* __restrict__ sb0, float* __restrict__ o0,
                         const float* __restrict__ sw1, const float* __restrict__ sb1, float* __restrict__ o1,
                         const float* __restrict__ sw2, const float* __restrict__ sb2, float* __restrict__ o2){
    __shared__ float wl[512];
    const int b = blockIdx.x, l = blockIdx.y, tid = threadIdx.x;
    const float* sw = (l==0) ? sw0 : (l==1 ? sw1 : sw2);
    const float* sb = (l==0) ? sb0 : (l==1 ? sb1 : sb2);
    float* so       = (l==0) ? o0  : (l==1 ? o1  : o2);
    wl[tid]       = w[b*512 + tid];
    wl[tid + 256] = w[b*512 + 256 + tid];
    __syncthreads();
    const float c = 0.044194173824159216f; // 1/sqrt(512)
    for (int cc = tid; cc < 512; cc += 256){
        const float4* row = (const float4*)(sw + cc*512);
        float acc = 0.f;
        #pragma unroll 4
        for (int dd = 0; dd < 128; ++dd){
            float4 v = row[dd];
            float4 wv = ((const float4*)wl)[dd];
            acc += v.x*wv.x + v.y*wv.y + v.z*wv.z + v.w*wv.w;
        }
        so[b*512 + cc] = acc * c + sb[cc];
    }
}

// ---------------- W2[o,i] = c^2 * sum_t conv_w[o,i,t]^2  (both layers) --------
__global__ void k_w2(const float* __restrict__ cw1, const float* __restrict__ cw2,
                     float* __restrict__ w2_1, float* __restrict__ w2_2){
    int gid = blockIdx.x*256 + threadIdx.x;     // 2 * 262144
    int layer = gid >> 18; int r = gid & 262143;
    const float* cw = layer ? cw2 : cw1;
    float* w2 = layer ? w2_2 : w2_1;
    const float c2 = 1.0f/4608.0f;
    const float* p = cw + r*9;
    float sum = 0.f;
    #pragma unroll
    for (int t=0;t<9;++t){ float v = p[t]; sum += v*v; }
    w2[r] = sum * c2;
}

// ---------------- d[b,o] = rsqrt( sum_i W2[o,i]*s[b,i]^2 + 1e-8 ) -------------
__global__ void k_demod2(const float* __restrict__ w21, const float* __restrict__ w22,
                         const float* __restrict__ s1,  const float* __restrict__ s2,
                         float* __restrict__ d1, float* __restrict__ d2){
    __shared__ float s2l[512];
    const int b = blockIdx.x, l = blockIdx.y, o = threadIdx.x;
    const float* w2 = l ? w22 : w21;
    const float* s  = l ? s2  : s1;
    float* d        = l ? d2  : d1;
    float sv = s[b*512 + o]; s2l[o] = sv*sv;
    __syncthreads();
    const float4* row = (const float4*)(w2 + o*512);
    const float4* sq  = (const float4*)s2l;
    float acc = 0.f;
    #pragma unroll 4
    for (int i=0;i<128;++i){
        float4 a = row[i], bq = sq[i];
        acc += a.x*bq.x + a.y*bq.y + a.z*bq.z + a.w*bq.w;
    }
    d[b*512 + o] = rsqrtf(acc + 1e-8f);
}

// ---------------- pack conv weights -> MFMA A-fragment order, bf16 ------------
// layout: wpk[t(9)][cb(16)][ofr(32)][lane(64)][j(8)] ; element =
//   c * conv_w[o = ofr*16 + (lane&15)][i = cb*32 + (lane>>4)*8 + j][t/3][t%3]
__global__ void k_pack(const float* __restrict__ cw1, const float* __restrict__ cw2,
                       uint4* __restrict__ wpk1, uint4* __restrict__ wpk2){
    int gid = blockIdx.x*256 + threadIdx.x;     // 2 * 294912
    int layer = (gid >= 294912);
    int r = layer ? gid - 294912 : gid;
    const float* cw = layer ? cw2 : cw1;
    uint4* dst = layer ? wpk2 : wpk1;
    int lane = r & 63;
    int ofr  = (r>>6) & 31;
    int cb   = (r>>11) & 15;
    int t    = r>>15;
    int o  = ofr*16 + (lane&15);
    int i0 = cb*32 + (lane>>4)*8;
    const float c = 0.014731391274719738f; // 1/sqrt(4608)
    const float* src = cw + (o*512 + i0)*9 + t;
    float f[8];
    #pragma unroll
    for (int j=0;j<8;++j) f[j] = src[j*9]*c;
    uint4 wv;
    wv.x = pk2(f[0],f[1]); wv.y = pk2(f[2],f[3]);
    wv.z = pk2(f[4],f[5]); wv.w = pk2(f[6],f[7]);
    dst[r] = wv;
}

// ---------------- pre-stage x*s -> global tiles (one tile per block) ----------
// Tile (b, rb, cb): 25344B, byte-identical to round-10/13's k_stage_g output:
// rows rb*4-1..rb*4+4 stored 0..5, 66 cols w/ halo, XOR-swizzled, bf16(x*s).
__global__ void k_stage_g(const float* __restrict__ x, const float* __restrict__ s,
                          char* __restrict__ xpg){
    const int tid = threadIdx.x;
    const int cb = blockIdx.x, rb = blockIdx.y, b = blockIdx.z;
    const int r0 = rb*4;
    const int scol   = tid & 63;
    const int schunk = (tid>>6) & 3;
    unsigned wcol = (unsigned)((scol+1)*64 + schunk*16);
    wcol ^= (unsigned)((((scol+1)>>1)&3)<<4);
    float sv[8];
    const float* sp8 = s + b*512 + cb*32 + schunk*8;
    #pragma unroll
    for (int j=0;j<8;++j) sv[j] = sp8[j];
    char* dst = xpg + ((size_t)((b*16 + rb)*16 + cb))*TILE6;
    const float* srcbase = x + (size_t)b*(512*PIX) + (size_t)(cb*32 + schunk*8)*PIX + scol;
    #pragma unroll
    for (int row=0; row<6; ++row){
        int gr = r0 - 1 + row;
        uint4 wq = make_uint4(0u,0u,0u,0u);
        if (0 <= gr && gr < 64){
            const float* sp = srcbase + gr*64;
            float f0 = sp[0*PIX]*sv[0], f1 = sp[1*PIX]*sv[1];
            float f2 = sp[2*PIX]*sv[2], f3 = sp[3*PIX]*sv[3];
            float f4 = sp[4*PIX]*sv[4], f5 = sp[5*PIX]*sv[5];
            float f6 = sp[6*PIX]*sv[6], f7 = sp[7*PIX]*sv[7];
            wq.x = pk2(f0,f1); wq.y = pk2(f2,f3);
            wq.z = pk2(f4,f5); wq.w = pk2(f6,f7);
        }
        *(uint4*)(dst + row*ROWB + wcol) = wq;
    }
    if (tid < 48){  // halo cols (image col -1 and 64) -> zeros
        int row = tid>>3; int hc = (tid&4) ? 65 : 0; int ck = tid&3;
        unsigned a = (unsigned)((row*66 + hc)*64 + ck*16);
        a ^= (unsigned)(((hc>>1)&3)<<4);
        *(uint4*)(dst + a) = make_uint4(0u,0u,0u,0u);
    }
}

// ---------------- the modulated 3x3 conv (implicit GEMM, bf16 MFMA) -----------
// grid (2 obp, 32 rb, 16 b), 256 threads (4 waves). Wave wv: o in
// [obp*256 + wv*64, +64) over 2 rows x 64 cols: acc[4][8].
// K-loop restructured BY INPUT ROW: each of the 4 staged rows is ds_read once
// (12 fragments) and feeds out-row0 (taps t=ir*3+dxi, ir<3) and out-row1
// (t=(ir-1)*3+dxi, ir>0). LDS reads/cb/wave: 72 -> 48. Per-acc tap order is
// unchanged (t ascending 0..8) -> bit-identical numerics to rounds 11/13.
__global__ __launch_bounds__(256, 2)
void k_conv(const char* __restrict__ xpg, float* __restrict__ y,
            const unsigned short* __restrict__ wpk,
            const float* __restrict__ dmod, const float* __restrict__ noise,
            const float* __restrict__ nsp, const float* __restrict__ bias){
    __shared__ __align__(16) char smem[2*TILE4];   // 33792 B
    char* xh0 = smem;
    char* xh1 = smem + TILE4;

    const int tid  = threadIdx.x;
    const int obp  = blockIdx.x;        // 0..1: 256-channel o-group
    const int rb   = blockIdx.y;        // 0..31
    const int b    = blockIdx.z;
    const int r0   = rb*2;
    const int lane = tid & 63;
    const int wv   = tid >> 6;          // 0..3: 64-channel o-subgroup
    const int ln15 = lane & 15;
    const int hi   = lane >> 4;

    f32x4 acc[4][8];
    #pragma unroll
    for (int mi=0;mi<4;++mi)
        #pragma unroll
        for (int ni=0;ni<8;++ni) acc[mi][ni] = (f32x4)(0.f);

    // B-fragment column byte-offsets (col-XOR swizzle), per (dx+1, colgroup)
    unsigned bcol[3][4];
    #pragma unroll
    for (int dxi=0; dxi<3; ++dxi)
        #pragma unroll
        for (int ni=0; ni<4; ++ni){
            int xcol = ni*16 + ln15 + dxi;
            unsigned a = (unsigned)(xcol*64 + hi*16);
            a ^= (unsigned)(((xcol>>1)&3)<<4);
            bcol[dxi][ni] = a;
        }

    // 4-row slice (rows r0-1..r0+2) of the 6-row tile for RB=rb>>1
    const char* tbase = xpg + ((size_t)((b*16 + (rb>>1))*16))*TILE6
                            + (size_t)(rb&1)*2*ROWB;
    auto stage = [&](int cb2, char* dstb){
        const char* src = tbase + (size_t)cb2*TILE6;
        #pragma unroll
        for (int k=0;k<4;++k)
            gl_lds16(src + (size_t)(tid + k*256)*16, dstb + (tid + k*256)*16);
        if (tid < 32)
            gl_lds16(src + (size_t)(1024 + tid)*16, dstb + (1024 + tid)*16);
    };

    stage(0, xh0);

    // A-fragment base: ofr0 = (obp*256 + wv*64)/16 = obp*16 + wv*4
    const short8* wpf = (const short8*)wpk + (size_t)(obp*16 + wv*4)*64 + lane;

    #pragma unroll 2
    for (int cb=0; cb<16; ++cb){
        __syncthreads();                         // staged buffer ready; prev reads done
        const char* cur = (cb&1) ? xh1 : xh0;
        const short8* wp = wpf + (size_t)cb*(32*64);
        #pragma unroll
        for (int ir=0; ir<4; ++ir){
            // 12 B-fragments of input row ir (read once)
            short8 B[12];
            const char* rbase = cur + ir*ROWB;
            #pragma unroll
            for (int dxi=0; dxi<3; ++dxi)
                #pragma unroll
                for (int ni=0; ni<4; ++ni)
                    B[dxi*4+ni] = *(const short8*)(rbase + bcol[dxi][ni]);
            #pragma unroll
            for (int dxi=0; dxi<3; ++dxi){
                #pragma unroll
                for (int mi=0; mi<4; ++mi){
                    if (ir < 3){
                        short8 a0 = wp[(size_t)(ir*3+dxi)*(16*32*64) + mi*64];
                        #pragma unroll
                        for (int ni=0; ni<4; ++ni)
                            mfma_bf16(acc[mi][ni], a0, B[dxi*4+ni]);
                    }
                    if (ir > 0){
                        short8 a1 = wp[(size_t)((ir-1)*3+dxi)*(16*32*64) + mi*64];
                        #pragma unroll
                        for (int ni=0; ni<4; ++ni)
                            mfma_bf16(acc[mi][4+ni], a1, B[dxi*4+ni]);
                    }
                }
            }
            if (ir == 0 && cb+1 < 16) stage(cb+1, (cb&1) ? xh0 : xh1);
        }
    }

    // epilogue: y = lrelu(d*acc + ns*noise + bias); d/bias from global (L2-hot)
    const int obase = obp*256 + wv*64;
    const float nsv = nsp[0];
    const float* dgl = dmod + b*512 + obase;
    const float* bgl = bias + obase;
    float nz[8];
    #pragma unroll
    for (int ni=0;ni<8;++ni){
        int row = r0 + (ni>>2);
        nz[ni] = nsv * noise[b*PIX + row*64 + (ni&3)*16 + ln15];
    }
    float* yb = y + ((size_t)(b*512 + obase))*PIX;
    #pragma unroll
    for (int mi=0;mi<4;++mi){
        float dv[4], bv[4];
        #pragma unroll
        for (int r=0;r<4;++r){
            int ol = mi*16 + hi*4 + r;
            dv[r] = dgl[ol]; bv[r] = bgl[ol];
        }
        #pragma unroll
        for (int ni=0;ni<8;++ni){
            int row = r0 + (ni>>2);
            int col = (ni&3)*16 + ln15;
            #pragma unroll
            for (int r=0;r<4;++r){
                float v = acc[mi][ni][r]*dv[r] + nz[ni] + bv[r];
                v = fmaxf(v, 0.2f*v);
                yb[(size_t)(mi*16 + hi*4 + r)*PIX + row*64 + col] = v;
            }
        }
    }
}

// ---------------- to_rgb: 1x1 modulated conv (no demod) + bias + lrelu --------
__global__ void k_rgb(const float* __restrict__ x2, const float* __restrict__ srgb,
                      const float* __restrict__ cw, const float* __restrict__ bias,
                      float* __restrict__ out){
    __shared__ float4 wr[512];
    const int b = blockIdx.x, tid = threadIdx.x;
    const float c = 0.044194173824159216f; // 1/sqrt(512)
    for (int cc = tid; cc < 512; cc += 256){
        float sc = srgb[b*512 + cc]*c;
        wr[cc] = make_float4(cw[cc]*sc, cw[512+cc]*sc, cw[1024+cc]*sc, 0.f);
    }
    __syncthreads();
    int px = blockIdx.y*256 + tid;
    const float* xp = x2 + (size_t)b*(512*PIX) + px;
    float a0=0.f, a1=0.f, a2=0.f;
    #pragma unroll 4
    for (int i=0;i<512;++i){
        float xv = xp[(size_t)i*PIX];
        float4 wv = wr[i];
        a0 += wv.x*xv; a1 += wv.y*xv; a2 += wv.z*xv;
    }
    a0 += bias[0]; a1 += bias[1]; a2 += bias[2];
    out[(size_t)(b*3+0)*PIX + px] = fmaxf(a0, 0.2f*a0);
    out[(size_t)(b*3+1)*PIX + px] = fmaxf(a1, 0.2f*a1);
    out[(size_t)(b*3+2)*PIX + px] = fmaxf(a2, 0.2f*a2);
}

extern "C" void kernel_launch(void* const* d_in, const int* in_sizes, int n_in,
                              void* d_out, int out_size, void* d_ws, size_t ws_size,
                              hipStream_t stream) {
    const float* x    = (const float*)d_in[0];
    const float* w    = (const float*)d_in[1];
    const float* n1   = (const float*)d_in[2];
    const float* n2   = (const float*)d_in[3];
    const float* s1w  = (const float*)d_in[4];
    const float* s1b  = (const float*)d_in[5];
    const float* c1w  = (const float*)d_in[6];
    const float* ns1  = (const float*)d_in[7];
    const float* b1   = (const float*)d_in[8];
    const float* s2w  = (const float*)d_in[9];
    const float* s2b  = (const float*)d_in[10];
    const float* c2w  = (const float*)d_in[11];
    const float* ns2  = (const float*)d_in[12];
    const float* b2   = (const float*)d_in[13];
    const float* rw   = (const float*)d_in[14];
    const float* rbv  = (const float*)d_in[15];
    const float* rcw  = (const float*)d_in[16];
    const float* rbias= (const float*)d_in[17];

    float* out_x   = (float*)d_out;
    float* out_rgb = out_x + (size_t)16*512*PIX;

    // workspace (round-13-proven layout): xpg = 16*16*16*25344 = 103,809,024 B
    // -> ws end 115.5 MB. f32 intermediate x1 lives in d_out x-region (scratch
    // until conv2 overwrites it with the final x).
    char* ws = (char*)d_ws;
    float* s1   = (float*)(ws + 0);
    float* s2   = (float*)(ws + 32768);
    float* srgb = (float*)(ws + 65536);
    float* d1   = (float*)(ws + 98304);
    float* d2   = (float*)(ws + 131072);
    float* w21  = (float*)(ws + 163840);
    float* w22  = (float*)(ws + 163840 + 1048576);
    unsigned short* wp1 = (unsigned short*)(ws + 2260992);
    unsigned short* wp2 = wp1 + 2359296;
    char* xpg   = ws + 11698176;
    float* x1   = out_x;

    k_style3<<<dim3(16,3), 256, 0, stream>>>(w, s1w, s1b, s1, s2w, s2b, s2, rw, rbv, srgb);
    k_w2<<<2048, 256, 0, stream>>>(c1w, c2w, w21, w22);
    k_pack<<<2304, 256, 0, stream>>>(c1w, c2w, (uint4*)wp1, (uint4*)wp2);
    k_demod2<<<dim3(16,2), 512, 0, stream>>>(w21, w22, s1, s2, d1, d2);

    dim3 cg(2, 32, 16);
    k_stage_g<<<dim3(16,16,16), 256, 0, stream>>>(x, s1, xpg);
    k_conv<<<cg, 256, 0, stream>>>(xpg, x1, wp1, d1, n1, ns1, b1);
    k_stage_g<<<dim3(16,16,16), 256, 0, stream>>>(x1, s2, xpg);
    k_conv<<<cg, 256, 0, stream>>>(xpg, out_x, wp2, d2, n2, ns2, b2);
    k_rgb<<<dim3(16,16), 256, 0, stream>>>(out_x, srgb, rcw, rbias, out_rgb);
}

// Round 16
// 765.763 us; speedup vs baseline: 1.1053x; 1.0906x over previous
//
#include <hip/hip_runtime.h>
#include <hip/hip_bf16.h>

typedef float f32x4 __attribute__((ext_vector_type(4)));
typedef short short8 __attribute__((ext_vector_type(8)));

#define CC    512
#define PIX   4096          // 64*64
#define ROWB  4224          // 66 cols * 64 B
#define TILE6 25344         // 6 rows * 4224 (k_stage_g tile)
#define TILE4 16896         // 4 rows * 4224 (conv LDS tile)

__device__ __forceinline__ unsigned short f2bf(float f){
    __hip_bfloat16 h = __float2bfloat16(f);
    return __builtin_bit_cast(unsigned short, h);
}
__device__ __forceinline__ unsigned pk2(float a, float b){
    return (unsigned)f2bf(a) | ((unsigned)f2bf(b) << 16);
}
__device__ __forceinline__ void mfma_bf16(f32x4& c, short8 a, short8 b){
    asm("v_mfma_f32_16x16x32_bf16 %0, %1, %2, %0" : "+v"(c) : "v"(a), "v"(b));
}
__device__ __forceinline__ void gl_lds16(const void* g, void* l){
    __builtin_amdgcn_global_load_lds(
        (const __attribute__((address_space(1))) unsigned int*)g,
        (__attribute__((address_space(3))) unsigned int*)l, 16, 0, 0);
}

// ---------------- styles: s[b,c] = (1/sqrt(512)) * w[b,:] @ sw[c,:] + sb[c] ----
__global__ void k_style3(const float* __restrict__ w,
                         const float* __restrict__ sw0, const float* __restrict__ sb0, float* __restrict__ o0,
                         const float* __restrict__ sw1, const float* __restrict__ sb1, float* __restrict__ o1,
                         const float* __restrict__ sw2, const float* __restrict__ sb2, float* __restrict__ o2){
    __shared__ float wl[512];
    const int b = blockIdx.x, l = blockIdx.y, tid = threadIdx.x;
    const float* sw = (l==0) ? sw0 : (l==1 ? sw1 : sw2);
    const float* sb = (l==0) ? sb0 : (l==1 ? sb1 : sb2);
    float* so       = (l==0) ? o0  : (l==1 ? o1  : o2);
    wl[tid]       = w[b*512 + tid];
    wl[tid + 256] = w[b*512 + 256 + tid];
    __syncthreads();
    const float c = 0.044194173824159216f; // 1/sqrt(512)
    for (int cc = tid; cc < 512; cc += 256){
        const float4* row = (const float4*)(sw + cc*512);
        float acc = 0.f;
        #pragma unroll 4
        for (int dd = 0; dd < 128; ++dd){
            float4 v = row[dd];
            float4 wv = ((const float4*)wl)[dd];
            acc += v.x*wv.x + v.y*wv.y + v.z*wv.z + v.w*wv.w;
        }
        so[b*512 + cc] = acc * c + sb[cc];
    }
}

// ---------------- W2[o,i] = c^2 * sum_t conv_w[o,i,t]^2  (both layers) --------
__global__ void k_w2(const float* __restrict__ cw1, const float* __restrict__ cw2,
                     float* __restrict__ w2_1, float* __restrict__ w2_2){
    int gid = blockIdx.x*256 + threadIdx.x;     // 2 * 262144
    int layer = gid >> 18; int r = gid & 262143;
    const float* cw = layer ? cw2 : cw1;
    float* w2 = layer ? w2_2 : w2_1;
    const float c2 = 1.0f/4608.0f;
    const float* p = cw + r*9;
    float sum = 0.f;
    #pragma unroll
    for (int t=0;t<9;++t){ float v = p[t]; sum += v*v; }
    w2[r] = sum * c2;
}

// ---------------- d[b,o] = rsqrt( sum_i W2[o,i]*s[b,i]^2 + 1e-8 ) -------------
__global__ void k_demod2(const float* __restrict__ w21, const float* __restrict__ w22,
                         const float* __restrict__ s1,  const float* __restrict__ s2,
                         float* __restrict__ d1, float* __restrict__ d2){
    __shared__ float s2l[512];
    const int b = blockIdx.x, l = blockIdx.y, o = threadIdx.x;
    const float* w2 = l ? w22 : w21;
    const float* s  = l ? s2  : s1;
    float* d        = l ? d2  : d1;
    float sv = s[b*512 + o]; s2l[o] = sv*sv;
    __syncthreads();
    const float4* row = (const float4*)(w2 + o*512);
    const float4* sq  = (const float4*)s2l;
    float acc = 0.f;
    #pragma unroll 4
    for (int i=0;i<128;++i){
        float4 a = row[i], bq = sq[i];
        acc += a.x*bq.x + a.y*bq.y + a.z*bq.z + a.w*bq.w;
    }
    d[b*512 + o] = rsqrtf(acc + 1e-8f);
}

// ---------------- pack conv weights -> MFMA A-fragment order, bf16 ------------
// layout: wpk[t(9)][cb(16)][ofr(32)][lane(64)][j(8)] ; element =
//   c * conv_w[o = ofr*16 + (lane&15)][i = cb*32 + (lane>>4)*8 + j][t/3][t%3]
__global__ void k_pack(const float* __restrict__ cw1, const float* __restrict__ cw2,
                       uint4* __restrict__ wpk1, uint4* __restrict__ wpk2){
    int gid = blockIdx.x*256 + threadIdx.x;     // 2 * 294912
    int layer = (gid >= 294912);
    int r = layer ? gid - 294912 : gid;
    const float* cw = layer ? cw2 : cw1;
    uint4* dst = layer ? wpk2 : wpk1;
    int lane = r & 63;
    int ofr  = (r>>6) & 31;
    int cb   = (r>>11) & 15;
    int t    = r>>15;
    int o  = ofr*16 + (lane&15);
    int i0 = cb*32 + (lane>>4)*8;
    const float c = 0.014731391274719738f; // 1/sqrt(4608)
    const float* src = cw + (o*512 + i0)*9 + t;
    float f[8];
    #pragma unroll
    for (int j=0;j<8;++j) f[j] = src[j*9]*c;
    uint4 wv;
    wv.x = pk2(f[0],f[1]); wv.y = pk2(f[2],f[3]);
    wv.z = pk2(f[4],f[5]); wv.w = pk2(f[6],f[7]);
    dst[r] = wv;
}

// ---------------- pre-stage x*s -> global tiles (one tile per block) ----------
// Tile (b, rb, cb): 25344B, byte-identical to round-13/14's k_stage_g output:
// rows rb*4-1..rb*4+4 stored 0..5, 66 cols w/ halo, XOR-swizzled, bf16(x*s).
__global__ void k_stage_g(const float* __restrict__ x, const float* __restrict__ s,
                          char* __restrict__ xpg){
    const int tid = threadIdx.x;
    const int cb = blockIdx.x, rb = blockIdx.y, b = blockIdx.z;
    const int r0 = rb*4;
    const int scol   = tid & 63;
    const int schunk = (tid>>6) & 3;
    unsigned wcol = (unsigned)((scol+1)*64 + schunk*16);
    wcol ^= (unsigned)((((scol+1)>>1)&3)<<4);
    float sv[8];
    const float* sp8 = s + b*512 + cb*32 + schunk*8;
    #pragma unroll
    for (int j=0;j<8;++j) sv[j] = sp8[j];
    char* dst = xpg + ((size_t)((b*16 + rb)*16 + cb))*TILE6;
    const float* srcbase = x + (size_t)b*(512*PIX) + (size_t)(cb*32 + schunk*8)*PIX + scol;
    #pragma unroll
    for (int row=0; row<6; ++row){
        int gr = r0 - 1 + row;
        uint4 wq = make_uint4(0u,0u,0u,0u);
        if (0 <= gr && gr < 64){
            const float* sp = srcbase + gr*64;
            float f0 = sp[0*PIX]*sv[0], f1 = sp[1*PIX]*sv[1];
            float f2 = sp[2*PIX]*sv[2], f3 = sp[3*PIX]*sv[3];
            float f4 = sp[4*PIX]*sv[4], f5 = sp[5*PIX]*sv[5];
            float f6 = sp[6*PIX]*sv[6], f7 = sp[7*PIX]*sv[7];
            wq.x = pk2(f0,f1); wq.y = pk2(f2,f3);
            wq.z = pk2(f4,f5); wq.w = pk2(f6,f7);
        }
        *(uint4*)(dst + row*ROWB + wcol) = wq;
    }
    if (tid < 48){  // halo cols (image col -1 and 64) -> zeros
        int row = tid>>3; int hc = (tid&4) ? 65 : 0; int ck = tid&3;
        unsigned a = (unsigned)((row*66 + hc)*64 + ck*16);
        a ^= (unsigned)(((hc>>1)&3)<<4);
        *(uint4*)(dst + a) = make_uint4(0u,0u,0u,0u);
    }
}

// ---------------- the modulated 3x3 conv (implicit GEMM, bf16 MFMA) -----------
// grid (2 obp, 32 rb, 16 b), 256 threads (4 waves). Round-13-proven VERBATIM:
// wave wv owns o in [obp*256 + wv*64, +64) over 2 rows x 64 cols: acc[4][8].
// Staging: LINEAR 16896B gl_lds copy of the pre-packed 4-row slice (row offset
// (rb&1)*2 within the 6-row tile). Af(t=0) loaded BEFORE the gl_lds batch so
// the first MFMA never waits on staging (in-order VMEM queue).
__global__ __launch_bounds__(256, 2)
void k_conv(const char* __restrict__ xpg, float* __restrict__ y,
            const unsigned short* __restrict__ wpk,
            const float* __restrict__ dmod, const float* __restrict__ noise,
            const float* __restrict__ nsp, const float* __restrict__ bias){
    __shared__ __align__(16) char smem[2*TILE4];   // 33792 B
    char* xh0 = smem;
    char* xh1 = smem + TILE4;

    const int tid  = threadIdx.x;
    const int obp  = blockIdx.x;        // 0..1: 256-channel o-group
    const int rb   = blockIdx.y;        // 0..31
    const int b    = blockIdx.z;
    const int r0   = rb*2;
    const int lane = tid & 63;
    const int wv   = tid >> 6;          // 0..3: 64-channel o-subgroup
    const int ln15 = lane & 15;
    const int hi   = lane >> 4;

    f32x4 acc[4][8];
    #pragma unroll
    for (int mi=0;mi<4;++mi)
        #pragma unroll
        for (int ni=0;ni<8;++ni) acc[mi][ni] = (f32x4)(0.f);

    // B-fragment column byte-offsets (col-XOR swizzle), per (dx+1, colgroup)
    unsigned bcol[3][4];
    #pragma unroll
    for (int dxi=0; dxi<3; ++dxi)
        #pragma unroll
        for (int ni=0; ni<4; ++ni){
            int xcol = ni*16 + ln15 + dxi;
            unsigned a = (unsigned)(xcol*64 + hi*16);
            a ^= (unsigned)(((xcol>>1)&3)<<4);
            bcol[dxi][ni] = a;
        }

    // 4-row slice (rows r0-1..r0+2) of the 6-row tile for RB=rb>>1
    const char* tbase = xpg + ((size_t)((b*16 + (rb>>1))*16))*TILE6
                            + (size_t)(rb&1)*2*ROWB;
    auto stage = [&](int cb2, char* dstb){
        const char* src = tbase + (size_t)cb2*TILE6;
        #pragma unroll
        for (int k=0;k<4;++k)
            gl_lds16(src + (size_t)(tid + k*256)*16, dstb + (tid + k*256)*16);
        if (tid < 32)
            gl_lds16(src + (size_t)(1024 + tid)*16, dstb + (1024 + tid)*16);
    };

    stage(0, xh0);

    // A-fragment base: ofr0 = (obp*256 + wv*64)/16 = obp*16 + wv*4
    const short8* wpf = (const short8*)wpk + (size_t)(obp*16 + wv*4)*64 + lane;

    #pragma unroll 2
    for (int cb=0; cb<16; ++cb){
        __syncthreads();                         // staged buffer ready; prev reads done
        const short8* wp = wpf + (size_t)cb*(32*64);
        short8 Af[4];
        #pragma unroll
        for (int mi=0;mi<4;++mi) Af[mi] = wp[mi*64];   // t=0 A, before staging loads
        if (cb+1 < 16) stage(cb+1, (cb&1) ? xh0 : xh1);
        const char* cur = (cb&1) ? xh1 : xh0;
        #pragma unroll
        for (int t=0; t<9; ++t){
            const int dxi = t%3;                 // dx+1; t/3 = dy+1
            if (t > 0){
                #pragma unroll
                for (int mi=0;mi<4;++mi) Af[mi] = wp[(size_t)t*(16*32*64) + mi*64];
            }
            const char* rbase0 = cur + (t/3)*ROWB;            // output row r0
            const char* rbase1 = rbase0 + ROWB;               // output row r0+1
            short8 Bf[8];
            #pragma unroll
            for (int ni=0;ni<4;++ni) Bf[ni]   = *(const short8*)(rbase0 + bcol[dxi][ni]);
            #pragma unroll
            for (int ni=0;ni<4;++ni) Bf[4+ni] = *(const short8*)(rbase1 + bcol[dxi][ni]);
            #pragma unroll
            for (int ni=0;ni<8;++ni)
                #pragma unroll
                for (int mi=0;mi<4;++mi)
                    mfma_bf16(acc[mi][ni], Af[mi], Bf[ni]);
        }
    }

    // epilogue: y = lrelu(d*acc + ns*noise + bias); d/bias from global (L2-hot)
    const int obase = obp*256 + wv*64;
    const float nsv = nsp[0];
    const float* dgl = dmod + b*512 + obase;
    const float* bgl = bias + obase;
    float nz[8];
    #pragma unroll
    for (int ni=0;ni<8;++ni){
        int row = r0 + (ni>>2);
        nz[ni] = nsv * noise[b*PIX + row*64 + (ni&3)*16 + ln15];
    }
    float* yb = y + ((size_t)(b*512 + obase))*PIX;
    #pragma unroll
    for (int mi=0;mi<4;++mi){
        float dv[4], bv[4];
        #pragma unroll
        for (int r=0;r<4;++r){
            int ol = mi*16 + hi*4 + r;
            dv[r] = dgl[ol]; bv[r] = bgl[ol];
        }
        #pragma unroll
        for (int ni=0;ni<8;++ni){
            int row = r0 + (ni>>2);
            int col = (ni&3)*16 + ln15;
            #pragma unroll
            for (int r=0;r<4;++r){
                float v = acc[mi][ni][r]*dv[r] + nz[ni] + bv[r];
                v = fmaxf(v, 0.2f*v);
                yb[(size_t)(mi*16 + hi*4 + r)*PIX + row*64 + col] = v;
            }
        }
    }
}

// ---------------- to_rgb: 1x1 modulated conv (no demod) + bias + lrelu --------
__global__ void k_rgb(const float* __restrict__ x2, const float* __restrict__ srgb,
                      const float* __restrict__ cw, const float* __restrict__ bias,
                      float* __restrict__ out){
    __shared__ float4 wr[512];
    const int b = blockIdx.x, tid = threadIdx.x;
    const float c = 0.044194173824159216f; // 1/sqrt(512)
    for (int cc = tid; cc < 512; cc += 256){
        float sc = srgb[b*512 + cc]*c;
        wr[cc] = make_float4(cw[cc]*sc, cw[512+cc]*sc, cw[1024+cc]*sc, 0.f);
    }
    __syncthreads();
    int px = blockIdx.y*256 + tid;
    const float* xp = x2 + (size_t)b*(512*PIX) + px;
    float a0=0.f, a1=0.f, a2=0.f;
    #pragma unroll 4
    for (int i=0;i<512;++i){
        float xv = xp[(size_t)i*PIX];
        float4 wv = wr[i];
        a0 += wv.x*xv; a1 += wv.y*xv; a2 += wv.z*xv;
    }
    a0 += bias[0]; a1 += bias[1]; a2 += bias[2];
    out[(size_t)(b*3+0)*PIX + px] = fmaxf(a0, 0.2f*a0);
    out[(size_t)(b*3+1)*PIX + px] = fmaxf(a1, 0.2f*a1);
    out[(size_t)(b*3+2)*PIX + px] = fmaxf(a2, 0.2f*a2);
}

extern "C" void kernel_launch(void* const* d_in, const int* in_sizes, int n_in,
                              void* d_out, int out_size, void* d_ws, size_t ws_size,
                              hipStream_t stream) {
    const float* x    = (const float*)d_in[0];
    const float* w    = (const float*)d_in[1];
    const float* n1   = (const float*)d_in[2];
    const float* n2   = (const float*)d_in[3];
    const float* s1w  = (const float*)d_in[4];
    const float* s1b  = (const float*)d_in[5];
    const float* c1w  = (const float*)d_in[6];
    const float* ns1  = (const float*)d_in[7];
    const float* b1   = (const float*)d_in[8];
    const float* s2w  = (const float*)d_in[9];
    const float* s2b  = (const float*)d_in[10];
    const float* c2w  = (const float*)d_in[11];
    const float* ns2  = (const float*)d_in[12];
    const float* b2   = (const float*)d_in[13];
    const float* rw   = (const float*)d_in[14];
    const float* rbv  = (const float*)d_in[15];
    const float* rcw  = (const float*)d_in[16];
    const float* rbias= (const float*)d_in[17];

    float* out_x   = (float*)d_out;
    float* out_rgb = out_x + (size_t)16*512*PIX;

    // workspace (round-13-proven layout): xpg = 16*16*16*25344 = 103,809,024 B
    // -> ws end 115.5 MB. f32 intermediate x1 lives in d_out x-region (scratch
    // until conv2 overwrites it with the final x).
    char* ws = (char*)d_ws;
    float* s1   = (float*)(ws + 0);
    float* s2   = (float*)(ws + 32768);
    float* srgb = (float*)(ws + 65536);
    float* d1   = (float*)(ws + 98304);
    float* d2   = (float*)(ws + 131072);
    float* w21  = (float*)(ws + 163840);
    float* w22  = (float*)(ws + 163840 + 1048576);
    unsigned short* wp1 = (unsigned short*)(ws + 2260992);
    unsigned short* wp2 = wp1 + 2359296;
    char* xpg   = ws + 11698176;
    float* x1   = out_x;

    k_style3<<<dim3(16,3), 256, 0, stream>>>(w, s1w, s1b, s1, s2w, s2b, s2, rw, rbv, srgb);
    k_w2<<<2048, 256, 0, stream>>>(c1w, c2w, w21, w22);
    k_pack<<<2304, 256, 0, stream>>>(c1w, c2w, (uint4*)wp1, (uint4*)wp2);
    k_demod2<<<dim3(16,2), 512, 0, stream>>>(w21, w22, s1, s2, d1, d2);

    dim3 cg(2, 32, 16);
    k_stage_g<<<dim3(16,16,16), 256, 0, stream>>>(x, s1, xpg);
    k_conv<<<cg, 256, 0, stream>>>(xpg, x1, wp1, d1, n1, ns1, b1);
    k_stage_g<<<dim3(16,16,16), 256, 0, stream>>>(x1, s2, xpg);
    k_conv<<<cg, 256, 0, stream>>>(xpg, out_x, wp2, d2, n2, ns2, b2);
    k_rgb<<<dim3(16,16), 256, 0, stream>>>(out_x, srgb, rcw, rbias, out_rgb);
}